// Round 11
// baseline (351.653 us; speedup 1.0000x reference)
//
#include <hip/hip_runtime.h>
#include <hip/hip_fp16.h>
#include <math.h>

#define NODES 100000
#define EDGES 1250000
#define HD 64
#define NFD 16
#define CHUNK 1024
#define NCHUNK ((NODES + CHUNK - 1) / CHUNK)
#define BN_INV 0.9999950000374996f  // 1/sqrt(1+1e-5)
#define LP 65  // LDS row pitch: 65 % 32 == 1 -> 2-way bank aliasing (free)

// ---------------- graph build ----------------

__global__ void k_hist(const int* __restrict__ ei, int* __restrict__ deg) {
  int e = blockIdx.x * blockDim.x + threadIdx.x;
  if (e < EDGES) atomicAdd(&deg[ei[EDGES + e]], 1);
}

__global__ void k_scan1(const int* __restrict__ deg, int* __restrict__ part) {
  __shared__ int lds[256];
  int t = threadIdx.x, b = blockIdx.x;
  int base = b * CHUNK + t * 4;
  int s = 0;
#pragma unroll
  for (int m = 0; m < 4; m++) { int i = base + m; if (i < NODES) s += deg[i]; }
  lds[t] = s; __syncthreads();
  for (int off = 128; off > 0; off >>= 1) {
    if (t < off) lds[t] += lds[t + off];
    __syncthreads();
  }
  if (t == 0) part[b] = lds[0];
}

__global__ void k_scan2(int* __restrict__ part) {
  if (threadIdx.x == 0 && blockIdx.x == 0) {
    int run = 0;
    for (int c = 0; c < NCHUNK; c++) { int v = part[c]; part[c] = run; run += v; }
  }
}

__global__ void k_scan3(const int* __restrict__ deg, const int* __restrict__ part,
                        int* __restrict__ rowptr, int* __restrict__ cur,
                        float* __restrict__ dis) {
  __shared__ int lds[256];
  int t = threadIdx.x, b = blockIdx.x;
  int base = b * CHUNK + t * 4;
  int dl[4]; int s = 0;
#pragma unroll
  for (int m = 0; m < 4; m++) { int i = base + m; dl[m] = (i < NODES) ? deg[i] : 0; s += dl[m]; }
  lds[t] = s; __syncthreads();
  for (int off = 1; off < 256; off <<= 1) {
    int add = (t >= off) ? lds[t - off] : 0;
    __syncthreads();
    lds[t] += add;
    __syncthreads();
  }
  int run = part[b] + lds[t] - s;  // exclusive prefix for this thread
#pragma unroll
  for (int m = 0; m < 4; m++) {
    int i = base + m;
    if (i < NODES) {
      rowptr[i] = run; cur[i] = run;
      dis[i] = 1.0f / sqrtf((float)(dl[m] + 1));  // GCN: indeg + self-loop
    }
    run += dl[m];
  }
  if (b == 0 && t == 0) rowptr[NODES] = EDGES;
}

// attention coeff in ORIGINAL edge order, then single 8B scattered write
__global__ void k_fillatt(const int* __restrict__ ei, const float* __restrict__ ea,
                          const float* __restrict__ cvec, const float* __restrict__ dvec,
                          const float* __restrict__ Wa, const float* __restrict__ ba,
                          int* __restrict__ cur, float2* __restrict__ sa) {
  int e = blockIdx.x * blockDim.x + threadIdx.x;
  if (e >= EDGES) return;
  int s = ei[e], d = ei[EDGES + e];
  float alin = cvec[d] + dvec[s] + ea[3 * e] * Wa[128] + ea[3 * e + 1] * Wa[129] +
               ea[3 * e + 2] * Wa[130] + ba[0];
  float lr = alin >= 0.f ? alin : 0.01f * alin;
  float a = 1.f / (1.f + expf(-lr));
  int p = atomicAdd(&cur[d], 1);
  sa[p] = make_float2(__int_as_float(s), a);
}

// ---------------- fp16 helpers ----------------

__device__ __forceinline__ void store16h(__half* dst, const float* v) {
  uint u[8];
#pragma unroll
  for (int j = 0; j < 8; j++) {
    __half2 h = __float22half2_rn(make_float2(v[2 * j], v[2 * j + 1]));
    u[j] = *reinterpret_cast<uint*>(&h);
  }
  uint4* o = (uint4*)dst;
  o[0] = make_uint4(u[0], u[1], u[2], u[3]);
  o[1] = make_uint4(u[4], u[5], u[6], u[7]);
}

__device__ __forceinline__ void store8h(__half* dst, const float* v) {
  uint u[4];
#pragma unroll
  for (int j = 0; j < 4; j++) {
    __half2 h = __float22half2_rn(make_float2(v[2 * j], v[2 * j + 1]));
    u[j] = *reinterpret_cast<uint*>(&h);
  }
  *(uint4*)dst = make_uint4(u[0], u[1], u[2], u[3]);
}

// one 16-edge gather step (4 edge slots x 16 col-lanes), fp16 rows
__device__ __forceinline__ void gstep(const __half* __restrict__ tab,
                                      const float2* __restrict__ sa,
                                      int m, int end, int last, int sub, int col,
                                      bool weighted,
                                      float4& A0, float4& A1, float4& A2, float4& A3) {
  int e0 = m + sub, e1 = e0 + 4, e2 = e0 + 8, e3 = e0 + 12;
  float2 s0 = sa[min(e0, last)], s1 = sa[min(e1, last)];
  float2 s2 = sa[min(e2, last)], s3 = sa[min(e3, last)];
  float w0 = (e0 < end) ? (weighted ? s0.y : 1.f) : 0.f;
  float w1 = (e1 < end) ? (weighted ? s1.y : 1.f) : 0.f;
  float w2 = (e2 < end) ? (weighted ? s2.y : 1.f) : 0.f;
  float w3 = (e3 < end) ? (weighted ? s3.y : 1.f) : 0.f;
  uint2 u0 = *((const uint2*)(tab + (size_t)__float_as_int(s0.x) * HD) + col);
  uint2 u1 = *((const uint2*)(tab + (size_t)__float_as_int(s1.x) * HD) + col);
  uint2 u2 = *((const uint2*)(tab + (size_t)__float_as_int(s2.x) * HD) + col);
  uint2 u3 = *((const uint2*)(tab + (size_t)__float_as_int(s3.x) * HD) + col);
  {
    float2 fa = __half22float2(*reinterpret_cast<__half2*>(&u0.x));
    float2 fb = __half22float2(*reinterpret_cast<__half2*>(&u0.y));
    A0.x = fmaf(w0, fa.x, A0.x); A0.y = fmaf(w0, fa.y, A0.y);
    A0.z = fmaf(w0, fb.x, A0.z); A0.w = fmaf(w0, fb.y, A0.w);
  }
  {
    float2 fa = __half22float2(*reinterpret_cast<__half2*>(&u1.x));
    float2 fb = __half22float2(*reinterpret_cast<__half2*>(&u1.y));
    A1.x = fmaf(w1, fa.x, A1.x); A1.y = fmaf(w1, fa.y, A1.y);
    A1.z = fmaf(w1, fb.x, A1.z); A1.w = fmaf(w1, fb.y, A1.w);
  }
  {
    float2 fa = __half22float2(*reinterpret_cast<__half2*>(&u2.x));
    float2 fb = __half22float2(*reinterpret_cast<__half2*>(&u2.y));
    A2.x = fmaf(w2, fa.x, A2.x); A2.y = fmaf(w2, fa.y, A2.y);
    A2.z = fmaf(w2, fb.x, A2.z); A2.w = fmaf(w2, fb.y, A2.w);
  }
  {
    float2 fa = __half22float2(*reinterpret_cast<__half2*>(&u3.x));
    float2 fb = __half22float2(*reinterpret_cast<__half2*>(&u3.y));
    A3.x = fmaf(w3, fa.x, A3.x); A3.y = fmaf(w3, fa.y, A3.y);
    A3.z = fmaf(w3, fb.x, A3.z); A3.w = fmaf(w3, fb.y, A3.w);
  }
}

__device__ __forceinline__ float4 red4(float4 a0, float4 a1, float4 a2, float4 a3) {
  float4 r;
  r.x = (a0.x + a1.x) + (a2.x + a3.x);
  r.y = (a0.y + a1.y) + (a2.y + a3.y);
  r.z = (a0.z + a1.z) + (a2.z + a3.z);
  r.w = (a0.w + a1.w) + (a2.w + a3.w);
#pragma unroll
  for (int off = 16; off <= 32; off <<= 1) {
    r.x += __shfl_xor(r.x, off); r.y += __shfl_xor(r.y, off);
    r.z += __shfl_xor(r.z, off); r.w += __shfl_xor(r.w, off);
  }
  return r;
}

// fp16 gather macro for the standalone attention aggregation
#define AGG_BODY16(TABLE, WEIGHTED)                                              \
  float4 acc0 = make_float4(0.f, 0.f, 0.f, 0.f);                                 \
  float4 acc1 = make_float4(0.f, 0.f, 0.f, 0.f);                                 \
  float4 acc2 = make_float4(0.f, 0.f, 0.f, 0.f);                                 \
  float4 acc3 = make_float4(0.f, 0.f, 0.f, 0.f);                                 \
  int last = end - 1;                                                            \
  for (int m = start; m < end; m += 16)                                          \
    gstep(TABLE, sa, m, end, last, sub, col, WEIGHTED, acc0, acc1, acc2, acc3);  \
  float4 accr = red4(acc0, acc1, acc2, acc3);

// ---------------- kernels ----------------

// lin0: h = x@Wn + bn -> hA, LDS ; h0 = h@Wl + bl -> hB16 ; cvec/dvec dots
__global__ __launch_bounds__(256) void k_lin0(
    const float* __restrict__ x,
    const float* __restrict__ Wn, const float* __restrict__ bn,
    const float* __restrict__ Wl, const float* __restrict__ bl,
    const float* __restrict__ Wa,
    float* __restrict__ hA, __half* __restrict__ hB16,
    float* __restrict__ cvec, float* __restrict__ dvec) {
  __shared__ float sh[64 * LP];
  __shared__ float sc[4][64], sd[4][64];
  int slot = threadIdx.x & 63;
  int cc = __builtin_amdgcn_readfirstlane(threadIdx.x >> 6);
  int c0 = cc * 16;
  int n0 = blockIdx.x * 64 + slot;
  bool valid = n0 < NODES;
  int n = valid ? n0 : NODES - 1;
  const float4* xr = (const float4*)(x + (size_t)n * NFD);
  float acc[16];
#pragma unroll
  for (int j = 0; j < 16; j++) acc[j] = bn[c0 + j];
#pragma unroll
  for (int q = 0; q < 4; q++) {
    float4 xa = xr[q];
    float xs[4] = {xa.x, xa.y, xa.z, xa.w};
#pragma unroll
    for (int t = 0; t < 4; t++)
#pragma unroll
      for (int j = 0; j < 16; j++)
        acc[j] = fmaf(xs[t], Wn[(q * 4 + t) * HD + c0 + j], acc[j]);
  }
#pragma unroll
  for (int j = 0; j < 16; j++) sh[slot * LP + c0 + j] = acc[j];
  if (valid) {
    float4* o = (float4*)(hA + (size_t)n * HD + c0);
    o[0] = make_float4(acc[0], acc[1], acc[2], acc[3]);
    o[1] = make_float4(acc[4], acc[5], acc[6], acc[7]);
    o[2] = make_float4(acc[8], acc[9], acc[10], acc[11]);
    o[3] = make_float4(acc[12], acc[13], acc[14], acc[15]);
  }
  __syncthreads();
  float a2[16];
#pragma unroll
  for (int j = 0; j < 16; j++) a2[j] = bl[c0 + j];
#pragma unroll 8
  for (int k = 0; k < 64; k++) {
    float hk = sh[slot * LP + k];
#pragma unroll
    for (int j = 0; j < 16; j++)
      a2[j] = fmaf(hk, Wl[k * HD + c0 + j], a2[j]);
  }
  float cn = 0.f, dn = 0.f;
#pragma unroll
  for (int j = 0; j < 16; j++) {
    cn = fmaf(a2[j], Wa[c0 + j], cn);
    dn = fmaf(a2[j], Wa[64 + c0 + j], dn);
  }
  if (valid) store16h(hB16 + (size_t)n * HD + c0, a2);
  sc[cc][slot] = cn;
  sd[cc][slot] = dn;
  __syncthreads();
  if (cc == 0 && valid) {
    cvec[n] = sc[0][slot] + sc[1][slot] + sc[2][slot] + sc[3][slot];
    dvec[n] = sd[0][slot] + sd[1][slot] + sd[2][slot] + sd[3][slot];
  }
}

// layer0 aggregation: gather hB16, write hC (fp32) + hC16
__global__ __launch_bounds__(256) void k_agg_att(
    const float2* __restrict__ sa, const int* __restrict__ rowptr,
    const float* __restrict__ hA, const __half* __restrict__ hB16,
    const float* __restrict__ g, const float* __restrict__ bt,
    float* __restrict__ hC, __half* __restrict__ hC16) {
  int lane = threadIdx.x & 63;
  int node = __builtin_amdgcn_readfirstlane(blockIdx.x * 4 + (threadIdx.x >> 6));
  if (node >= NODES) return;
  int start = rowptr[node], end = rowptr[node + 1];
  int sub = lane >> 4, col = lane & 15;
  float4 gg = ((const float4*)g)[col];
  float4 bb = ((const float4*)bt)[col];
  float4 ha = *((const float4*)(hA + (size_t)node * HD) + col);
  AGG_BODY16(hB16, true)
  if (lane < 16) {
    float4 v;
    v.x = fmaxf(accr.x * (gg.x * BN_INV) + bb.x, 0.f) + ha.x;
    v.y = fmaxf(accr.y * (gg.y * BN_INV) + bb.y, 0.f) + ha.y;
    v.z = fmaxf(accr.z * (gg.z * BN_INV) + bb.z, 0.f) + ha.z;
    v.w = fmaxf(accr.w * (gg.w * BN_INV) + bb.w, 0.f) + ha.w;
    *((float4*)(hC + (size_t)node * HD) + col) = v;
    __half2 p0 = __float22half2_rn(make_float2(v.x, v.y));
    __half2 p1 = __float22half2_rn(make_float2(v.z, v.w));
    uint2 u;
    u.x = *reinterpret_cast<uint*>(&p0);
    u.y = *reinterpret_cast<uint*>(&p1);
    *((uint2*)(hC16 + (size_t)node * HD) + col) = u;
  }
}

// FUSED mean-gather (hC16) + SAGE + GCN pre-GEMM. 512 threads: 8 waves.
// phase 1: each wave gathers 8 nodes, 2 at a time (8 gathers in flight).
// phase 2: col-split 8/wave (c0 = wu*8, SGPR -> s_load weights).
__global__ __launch_bounds__(512) void k_msage(
    const float2* __restrict__ sa, const int* __restrict__ rowptr,
    const float* __restrict__ hC, const __half* __restrict__ hC16,
    const float* __restrict__ Wl, const float* __restrict__ bl,
    const float* __restrict__ Wr, const float* __restrict__ Wg,
    const float* __restrict__ g, const float* __restrict__ bt,
    const float* __restrict__ dis,
    float* __restrict__ hA, float* __restrict__ hD, __half* __restrict__ hD16) {
  __shared__ float sh[64 * LP];
  int lane = threadIdx.x & 63;
  int wu = __builtin_amdgcn_readfirstlane(threadIdx.x >> 6);  // 0..7
  int sub = lane >> 4, col = lane & 15;
  int nbase = blockIdx.x * 64;
  // phase 1: mean-gather, 2 nodes interleaved
  for (int i = 0; i < 8; i += 2) {
    int slotA = wu * 8 + i, slotB = slotA + 1;
    int nA = min(nbase + slotA, NODES - 1);
    int nB = min(nbase + slotB, NODES - 1);
    int sA = rowptr[nA], eA = rowptr[nA + 1];
    int sB = rowptr[nB], eB = rowptr[nB + 1];
    int lenA = eA - sA, lenB = eB - sB;
    int lastA = (lenA > 0) ? eA - 1 : 0;
    int lastB = (lenB > 0) ? eB - 1 : 0;
    float rdA = 1.f / fmaxf((float)lenA, 1.f);
    float rdB = 1.f / fmaxf((float)lenB, 1.f);
    float4 A0 = make_float4(0, 0, 0, 0), A1 = A0, A2 = A0, A3 = A0;
    float4 B0 = A0, B1 = A0, B2 = A0, B3 = A0;
    int iters = (max(lenA, lenB) + 15) >> 4;
    int mA = sA, mB = sB;
    for (int it = 0; it < iters; ++it, mA += 16, mB += 16) {
      gstep(hC16, sa, mA, eA, lastA, sub, col, false, A0, A1, A2, A3);
      gstep(hC16, sa, mB, eB, lastB, sub, col, false, B0, B1, B2, B3);
    }
    float4 ra = red4(A0, A1, A2, A3);
    float4 rb = red4(B0, B1, B2, B3);
    if (lane < 16) {
      sh[slotA * LP + col * 4 + 0] = ra.x * rdA;
      sh[slotA * LP + col * 4 + 1] = ra.y * rdA;
      sh[slotA * LP + col * 4 + 2] = ra.z * rdA;
      sh[slotA * LP + col * 4 + 3] = ra.w * rdA;
      sh[slotB * LP + col * 4 + 0] = rb.x * rdB;
      sh[slotB * LP + col * 4 + 1] = rb.y * rdB;
      sh[slotB * LP + col * 4 + 2] = rb.z * rdB;
      sh[slotB * LP + col * 4 + 3] = rb.w * rdB;
    }
  }
  __syncthreads();
  // phase 2: GEMMs, 8 cols per wave
  int c0 = wu * 8;
  int n0 = nbase + lane;
  bool valid = n0 < NODES;
  int n = valid ? n0 : NODES - 1;
  const float4* cr = (const float4*)(hC + (size_t)n * HD);
  float acc[8];
#pragma unroll
  for (int j = 0; j < 8; j++) acc[j] = bl[c0 + j];
#pragma unroll 8
  for (int k = 0; k < 64; k++) {
    float mk = sh[lane * LP + k];
#pragma unroll
    for (int j = 0; j < 8; j++)
      acc[j] = fmaf(mk, Wl[k * HD + c0 + j], acc[j]);
  }
#pragma unroll 4
  for (int q = 0; q < 16; q++) {
    float4 ac = cr[q];
    float cs[4] = {ac.x, ac.y, ac.z, ac.w};
#pragma unroll
    for (int t = 0; t < 4; t++)
#pragma unroll
      for (int j = 0; j < 8; j++)
        acc[j] = fmaf(cs[t], Wr[(q * 4 + t) * HD + c0 + j], acc[j]);
  }
  float tv[8];
  {
    float4 r0 = cr[wu * 2], r1 = cr[wu * 2 + 1];
    float rv[8] = {r0.x, r0.y, r0.z, r0.w, r1.x, r1.y, r1.z, r1.w};
#pragma unroll
    for (int j = 0; j < 8; j++)
      tv[j] = fmaxf(acc[j] * (g[c0 + j] * BN_INV) + bt[c0 + j], 0.f) + rv[j];
  }
  __syncthreads();  // mean rows fully consumed -> safe to overwrite
#pragma unroll
  for (int j = 0; j < 8; j++) sh[lane * LP + c0 + j] = tv[j];
  if (valid) {
    float4* o = (float4*)(hA + (size_t)n * HD + c0);
    o[0] = make_float4(tv[0], tv[1], tv[2], tv[3]);
    o[1] = make_float4(tv[4], tv[5], tv[6], tv[7]);
  }
  __syncthreads();
  float di = dis[n];
  float a2[8];
#pragma unroll
  for (int j = 0; j < 8; j++) a2[j] = 0.f;
#pragma unroll 8
  for (int k = 0; k < 64; k++) {
    float tk = sh[lane * LP + k];
#pragma unroll
    for (int j = 0; j < 8; j++)
      a2[j] = fmaf(tk, Wg[k * HD + c0 + j], a2[j]);
  }
#pragma unroll
  for (int j = 0; j < 8; j++) a2[j] *= di;
  if (valid) {
    float4* o = (float4*)(hD + (size_t)n * HD + c0);
    o[0] = make_float4(a2[0], a2[1], a2[2], a2[3]);
    o[1] = make_float4(a2[4], a2[5], a2[6], a2[7]);
    store8h(hD16 + (size_t)n * HD + c0, a2);
  }
}

// FUSED GCN aggregation (gather hD16) + regressor head -> out. 512 threads.
__global__ __launch_bounds__(512) void k_gcnreg(
    const float2* __restrict__ sa, const int* __restrict__ rowptr,
    const float* __restrict__ dis,
    const float* __restrict__ hA,     // t (residual ident)
    const float* __restrict__ hD,     // fp32 self rows
    const __half* __restrict__ hD16,  // fp16 gather table
    const float* __restrict__ bg,
    const float* __restrict__ g, const float* __restrict__ bt,
    const float* __restrict__ W1, const float* __restrict__ b1,
    const float* __restrict__ W2, const float* __restrict__ b2,
    const float* __restrict__ W3, const float* __restrict__ b3,
    float* __restrict__ out) {
  __shared__ float sh[64 * LP];
  __shared__ float sred[8][64];
  int lane = threadIdx.x & 63;
  int wu = __builtin_amdgcn_readfirstlane(threadIdx.x >> 6);  // 0..7
  int sub = lane >> 4, col = lane & 15;
  int nbase = blockIdx.x * 64;
  float4 gg = ((const float4*)g)[col];
  float4 bb = ((const float4*)bt)[col];
  float4 bgv = ((const float4*)bg)[col];
  // phase 1: gcn-gather + epilogue, 2 nodes interleaved
  for (int i = 0; i < 8; i += 2) {
    int slotA = wu * 8 + i, slotB = slotA + 1;
    int nA = min(nbase + slotA, NODES - 1);
    int nB = min(nbase + slotB, NODES - 1);
    int sA = rowptr[nA], eA = rowptr[nA + 1];
    int sB = rowptr[nB], eB = rowptr[nB + 1];
    int lenA = eA - sA, lenB = eB - sB;
    int lastA = (lenA > 0) ? eA - 1 : 0;
    int lastB = (lenB > 0) ? eB - 1 : 0;
    float diA = dis[nA], diB = dis[nB];
    float4 svA = *((const float4*)(hD + (size_t)nA * HD) + col);
    float4 svB = *((const float4*)(hD + (size_t)nB * HD) + col);
    float4 haA = *((const float4*)(hA + (size_t)nA * HD) + col);
    float4 haB = *((const float4*)(hA + (size_t)nB * HD) + col);
    float4 A0 = make_float4(0, 0, 0, 0), A1 = A0, A2 = A0, A3 = A0;
    float4 B0 = A0, B1 = A0, B2 = A0, B3 = A0;
    int iters = (max(lenA, lenB) + 15) >> 4;
    int mA = sA, mB = sB;
    for (int it = 0; it < iters; ++it, mA += 16, mB += 16) {
      gstep(hD16, sa, mA, eA, lastA, sub, col, false, A0, A1, A2, A3);
      gstep(hD16, sa, mB, eB, lastB, sub, col, false, B0, B1, B2, B3);
    }
    float4 ra = red4(A0, A1, A2, A3);
    float4 rb = red4(B0, B1, B2, B3);
    if (lane < 16) {
      sh[slotA * LP + col * 4 + 0] =
          fmaxf((diA * (ra.x + svA.x) + bgv.x) * (gg.x * BN_INV) + bb.x, 0.f) + haA.x;
      sh[slotA * LP + col * 4 + 1] =
          fmaxf((diA * (ra.y + svA.y) + bgv.y) * (gg.y * BN_INV) + bb.y, 0.f) + haA.y;
      sh[slotA * LP + col * 4 + 2] =
          fmaxf((diA * (ra.z + svA.z) + bgv.z) * (gg.z * BN_INV) + bb.z, 0.f) + haA.z;
      sh[slotA * LP + col * 4 + 3] =
          fmaxf((diA * (ra.w + svA.w) + bgv.w) * (gg.w * BN_INV) + bb.w, 0.f) + haA.w;
      sh[slotB * LP + col * 4 + 0] =
          fmaxf((diB * (rb.x + svB.x) + bgv.x) * (gg.x * BN_INV) + bb.x, 0.f) + haB.x;
      sh[slotB * LP + col * 4 + 1] =
          fmaxf((diB * (rb.y + svB.y) + bgv.y) * (gg.y * BN_INV) + bb.y, 0.f) + haB.y;
      sh[slotB * LP + col * 4 + 2] =
          fmaxf((diB * (rb.z + svB.z) + bgv.z) * (gg.z * BN_INV) + bb.z, 0.f) + haB.z;
      sh[slotB * LP + col * 4 + 3] =
          fmaxf((diB * (rb.w + svB.w) + bgv.w) * (gg.w * BN_INV) + bb.w, 0.f) + haB.w;
    }
  }
  __syncthreads();
  // phase 2: regressor GEMM chain from LDS, 8 cols per wave
  int c0 = wu * 8;
  int n0 = nbase + lane;
  bool valid = n0 < NODES;
  int n = valid ? n0 : NODES - 1;
  float acc[8];
#pragma unroll
  for (int j = 0; j < 8; j++) acc[j] = b1[c0 + j];
#pragma unroll 8
  for (int k = 0; k < 64; k++) {
    float rk = sh[lane * LP + k];
#pragma unroll
    for (int j = 0; j < 8; j++)
      acc[j] = fmaf(rk, W1[k * HD + c0 + j], acc[j]);
  }
  float t1v[8];
#pragma unroll
  for (int j = 0; j < 8; j++) t1v[j] = fmaxf(acc[j], 0.f);
  __syncthreads();  // layer2 rows consumed -> overwrite with t1
#pragma unroll
  for (int j = 0; j < 8; j++) sh[lane * LP + c0 + j] = t1v[j];
  __syncthreads();
  int d0 = wu * 4;
  float a2[4];
#pragma unroll
  for (int j = 0; j < 4; j++) a2[j] = b2[d0 + j];
#pragma unroll 8
  for (int k = 0; k < 64; k++) {
    float tk = sh[lane * LP + k];
#pragma unroll
    for (int j = 0; j < 4; j++)
      a2[j] = fmaf(tk, W2[k * 32 + d0 + j], a2[j]);
  }
  float part = 0.f;
#pragma unroll
  for (int j = 0; j < 4; j++) part = fmaf(fmaxf(a2[j], 0.f), W3[d0 + j], part);
  sred[wu][lane] = part;
  __syncthreads();
  if (wu == 0 && valid) {
    float s = b3[0];
#pragma unroll
    for (int w = 0; w < 8; w++) s += sred[w][lane];
    out[n] = s;
  }
}

// ---------------- host launch ----------------

extern "C" void kernel_launch(void* const* d_in, const int* in_sizes, int n_in,
                              void* d_out, int out_size, void* d_ws, size_t ws_size,
                              hipStream_t stream) {
  const float* x      = (const float*)d_in[0];
  const float* ea     = (const float*)d_in[1];
  const int*   ei     = (const int*)d_in[2];
  const float* W_node = (const float*)d_in[3];
  const float* b_node = (const float*)d_in[4];
  // d_in[5], d_in[6]: W_edge/b_edge — unused by the reference output
  const float* W_lin0 = (const float*)d_in[7];
  const float* b_lin0 = (const float*)d_in[8];
  const float* W_att0 = (const float*)d_in[9];
  const float* b_att0 = (const float*)d_in[10];
  const float* W_sl   = (const float*)d_in[11];
  const float* b_sl   = (const float*)d_in[12];
  const float* W_sr   = (const float*)d_in[13];
  const float* W_gcn  = (const float*)d_in[14];
  const float* b_gcn  = (const float*)d_in[15];
  const float* bn_g   = (const float*)d_in[16];  // [3,64]
  const float* bn_b   = (const float*)d_in[17];
  const float* W_r1   = (const float*)d_in[18];
  const float* b_r1   = (const float*)d_in[19];
  const float* W_r2   = (const float*)d_in[20];
  const float* b_r2   = (const float*)d_in[21];
  const float* W_r3   = (const float*)d_in[22];
  const float* b_r3   = (const float*)d_in[23];
  float* out = (float*)d_out;

  char* ws = (char*)d_ws;
  size_t o = 0;
  auto alloc = [&](size_t bytes) -> void* {
    void* p = ws + o;
    o += (bytes + 255) & ~(size_t)255;
    return p;
  };
  int*    deg    = (int*)alloc(NODES * 4);
  int*    rowptr = (int*)alloc((NODES + 1) * 4);
  int*    cur    = (int*)alloc(NODES * 4);
  int*    part   = (int*)alloc(256 * 4);
  float2* sa     = (float2*)alloc((size_t)EDGES * 8);
  float*  hA     = (float*)alloc((size_t)NODES * HD * 4);
  float*  hC     = (float*)alloc((size_t)NODES * HD * 4);
  float*  hD     = (float*)alloc((size_t)NODES * HD * 4);
  __half* hB16   = (__half*)alloc((size_t)NODES * HD * 2);
  __half* hC16   = (__half*)alloc((size_t)NODES * HD * 2);
  __half* hD16   = (__half*)alloc((size_t)NODES * HD * 2);
  float*  cvec   = (float*)alloc(NODES * 4);
  float*  dvec   = (float*)alloc(NODES * 4);
  float*  dis    = (float*)alloc(NODES * 4);
  (void)ws_size; (void)in_sizes; (void)n_in; (void)out_size;

  const int EB  = (EDGES + 255) / 256;
  const int NT  = (NODES + 63) / 64;     // 64 nodes/block
  const int NBW = (NODES + 3) / 4;       // wave-per-node (4 waves/block)

  hipMemsetAsync(deg, 0, NODES * 4, stream);
  k_hist<<<EB, 256, 0, stream>>>(ei, deg);
  k_scan1<<<NCHUNK, 256, 0, stream>>>(deg, part);
  k_scan2<<<1, 64, 0, stream>>>(part);
  k_scan3<<<NCHUNK, 256, 0, stream>>>(deg, part, rowptr, cur, dis);

  k_lin0<<<NT, 256, 0, stream>>>(x, W_node, b_node, W_lin0, b_lin0, W_att0,
                                 hA, hB16, cvec, dvec);
  k_fillatt<<<EB, 256, 0, stream>>>(ei, ea, cvec, dvec, W_att0, b_att0, cur, sa);
  k_agg_att<<<NBW, 256, 0, stream>>>(sa, rowptr, hA, hB16,
                                     bn_g + 0 * HD, bn_b + 0 * HD, hC, hC16);
  // fused mean-gather + SAGE + GCN pre-GEMM: t -> hA, hBp -> hD/hD16
  k_msage<<<NT, 512, 0, stream>>>(sa, rowptr, hC, hC16, W_sl, b_sl, W_sr, W_gcn,
                                  bn_g + 1 * HD, bn_b + 1 * HD, dis, hA, hD, hD16);
  // fused GCN aggregation + regressor -> out
  k_gcnreg<<<NT, 512, 0, stream>>>(sa, rowptr, dis, hA, hD, hD16, b_gcn,
                                   bn_g + 2 * HD, bn_b + 2 * HD,
                                   W_r1, b_r1, W_r2, b_r2, W_r3, b_r3, out);
}